// Round 12
// baseline (180.429 us; speedup 1.0000x reference)
//
#include <hip/hip_runtime.h>
#include <math.h>

constexpr int N   = 4096;   // nodes
constexpr int F   = 256;    // IN_FEAT (= NH*HID)
constexpr int NH  = 8;      // heads
constexpr int HID = 32;     // hidden per head
constexpr float SLOPE = 0.2f;

using h2       = __attribute__((ext_vector_type(2))) _Float16;
using frag_f16 = __attribute__((ext_vector_type(8))) _Float16;  // 4 VGPRs
using frag_cd  = __attribute__((ext_vector_type(4))) float;
using frag_c16 = __attribute__((ext_vector_type(16))) float;

__device__ inline unsigned short f2h(float x) {
  _Float16 v = (_Float16)x;
  unsigned short u; __builtin_memcpy(&u, &v, 2); return u;
}

// ================= K_U: U[c][k] = sum_f W[head*32+f][k] * a[side*32+f] =================
__global__ __launch_bounds__(256) void k_u(const float* __restrict__ W,
                                           const float* __restrict__ a,
                                           float* __restrict__ U) {
  const int c = blockIdx.x, k = threadIdx.x;
  const int head = c & 7, side = c >> 3;
  float acc = 0.f;
#pragma unroll
  for (int f = 0; f < 32; ++f)
    acc += W[(size_t)(head * 32 + f) * F + k] * a[side * 32 + f];
  U[c * F + k] = acc;
}

// ================= K_FRONT: everything before aggregation (ZERO LDS) =================
// [0,256):    s = h@U (U from global, L1-hot) -> RT2, BT, DT
// [256,512):  gT2 = (h @ W^T)^T fp16 via MFMA, 1 mt x 4 nt per wave (A reused 4x),
//             stored in MFMA-FRAGMENT ORDER: gT2[head][js][c8][ss][kh*32+n32][8].
// [512,2560): adjacency bitmask via __ballot: one v_cmp per 64 ints, NO DS ops.
// ROUND 12: launched TWICE (idempotent) as a timing instrument:
// dur(k_front) = wall_12 - 150.3us; dispatches should surface in top-5 w/ PMC.
__global__ __launch_bounds__(256) void k_front(const float* __restrict__ h,
                                               const float* __restrict__ W,
                                               const float* __restrict__ U,
                                               const int* __restrict__ adj,
                                               unsigned int* __restrict__ RT2,
                                               unsigned short* __restrict__ BT,
                                               unsigned short* __restrict__ DT,
                                               unsigned short* __restrict__ gT2,
                                               unsigned int* __restrict__ bits) {
  const int b = blockIdx.x, t = threadIdx.x;
  if (b < 256) {
    // ---- s-part: thread (r,c); h-row reads broadcast across the 16 c-threads ----
    const int i0 = b * 16;
    const int r = t >> 4, c = t & 15;
    const float4* hp = (const float4*)(h + (size_t)(i0 + r) * F);
    const float4* up = (const float4*)(U + (size_t)c * F);
    float acc = 0.f;
#pragma unroll
    for (int k4 = 0; k4 < 64; ++k4) {
      const float4 hv = hp[k4];
      const float4 uv = up[k4];
      acc += hv.x * uv.x + hv.y * uv.y + hv.z * uv.z + hv.w * uv.w;
    }
    const int n = i0 + r;
    if (c < 8) {
      const unsigned int r16 = f2h(__expf(-0.8f * acc));
      RT2[(size_t)n * NH + c] = (r16 << 16) | r16;
    } else {
      const int hd = c - 8;
      BT[(size_t)hd * N + n] = f2h(__expf(acc));
      DT[(size_t)hd * N + n] = f2h(__expf(SLOPE * acc));
    }
  } else if (b < 512) {
    // ---- gT2 GEMM: one wave per 16x64 strip (1 mt x 4 nt), A reused 4x ----
    const int lane = t & 63;
    const int tile = (b - 256) * 4 + (t >> 6);   // 0..1023
    const int mt = tile >> 2, nt4 = tile & 3;
    const int m0 = mt * 16, n0 = nt4 * 64;
    const int n16 = lane & 15, quad = lane >> 4;
    frag_cd acc[4];
#pragma unroll
    for (int j = 0; j < 4; ++j) acc[j] = frag_cd{0.f, 0.f, 0.f, 0.f};
    const float* ap = h + (size_t)(m0 + n16) * F + quad * 8;
    const float* bp = W + (size_t)(n0 + n16) * F + quad * 8;
#pragma unroll
    for (int ks = 0; ks < F / 32; ++ks) {
      const float4 a0 = *(const float4*)(ap + ks * 32);
      const float4 a1 = *(const float4*)(ap + ks * 32 + 4);
      const frag_f16 af = {(_Float16)a0.x, (_Float16)a0.y, (_Float16)a0.z, (_Float16)a0.w,
                           (_Float16)a1.x, (_Float16)a1.y, (_Float16)a1.z, (_Float16)a1.w};
#pragma unroll
      for (int j = 0; j < 4; ++j) {
        const float4 b0 = *(const float4*)(bp + (size_t)j * 16 * F + ks * 32);
        const float4 b1 = *(const float4*)(bp + (size_t)j * 16 * F + ks * 32 + 4);
        const frag_f16 bf = {(_Float16)b0.x, (_Float16)b0.y, (_Float16)b0.z, (_Float16)b0.w,
                             (_Float16)b1.x, (_Float16)b1.y, (_Float16)b1.z, (_Float16)b1.w};
        acc[j] = __builtin_amdgcn_mfma_f32_16x16x32_f16(af, bf, acc[j], 0, 0, 0);
      }
    }
    // fragment-order stores: (feature r, node m) -> gT2[head][js][c8][ss][kh*32+n32][e]
    const int m  = m0 + quad * 4;
    const int js_ = m >> 10, c8_ = (m >> 7) & 7, ss_ = (m >> 4) & 7;
    const int kh_ = (m >> 3) & 1, e_ = m & 7;  // e_ in {0,4}
#pragma unroll
    for (int j = 0; j < 4; ++j) {
      unsigned short tmp[4];
#pragma unroll
      for (int reg = 0; reg < 4; ++reg) tmp[reg] = f2h(acc[j][reg]);
      const int r = n0 + j * 16 + n16;         // feature row
      const int head_ = r >> 5, n32_ = r & 31;
      unsigned short* dst = gT2 + ((size_t)(head_ * 4 + js_) * 64 + (c8_ * 8 + ss_)) * 512
                                + (kh_ * 32 + n32_) * 8 + e_;
      *(int2*)dst = *(int2*)tmp;
    }
  } else {
    // ---- bitmask via ballot: lane l tests adj[base + q*64 + l]; one v_cmp
    // yields 64 bits (2 output words). Word w bit j = adj[row, w*32+j].
    const int lane = t & 63;
    const int wv   = t >> 6;
    const int row  = (b - 512) * 2 + (wv >> 1);
    const int half = wv & 1;  // each wave covers 2048 ints = 8 KB
    const int* src = adj + (size_t)row * N + half * 2048 + lane;
    unsigned int* dstw = bits + (size_t)row * (N / 32) + half * 64;
#pragma unroll
    for (int it = 0; it < 8; ++it) {
      const int v0 = src[it * 256];
      const int v1 = src[it * 256 + 64];
      const int v2 = src[it * 256 + 128];
      const int v3 = src[it * 256 + 192];
      const unsigned long long m0 = __ballot(v0 & 1);
      const unsigned long long m1 = __ballot(v1 & 1);
      const unsigned long long m2 = __ballot(v2 & 1);
      const unsigned long long m3 = __ballot(v3 & 1);
      if (lane < 8) {
        const unsigned long long ms = (lane & 4) ? ((lane & 2) ? m3 : m2)
                                                 : ((lane & 2) ? m1 : m0);
        const unsigned int w = (unsigned int)(ms >> ((lane & 1) * 32));
        dstw[it * 8 + lane] = w;
      }
    }
  }
}

// ================= K_AGG: 64i-tile 32x32 fp16-MFMA flash aggregation =================
// (unchanged; measured at 24.3us in round 11 — near its memory floor)
constexpr int TI = 64;
constexpr int NSPLIT = 4;

__global__ __launch_bounds__(256, 4) void k_agg(
    const unsigned short* __restrict__ gT2,
    const unsigned int* __restrict__ RT2,
    const unsigned short* __restrict__ BT, const unsigned short* __restrict__ DT,
    const unsigned int* __restrict__ bits,
    float* __restrict__ parts, float* __restrict__ lparts) {
  __shared__ __align__(16) uint4 sBD[2][2][128];         // [B/D][head][1024 fp16]

  const int t    = threadIdx.x;
  const int lane = t & 63;
  const int wv   = t >> 6;
  const int isub = wv & 1;
  const int hd   = wv >> 1;
  const int b    = blockIdx.x;
  const int hp   = b & 3;
  const int js   = (b >> 2) & (NSPLIT - 1);
  const int i0   = (b >> 4) * TI;
  const int head = hp * 2 + hd;

  const int n32 = lane & 31;
  const int kh  = lane >> 5;

  const int myi = i0 + isub * 32 + n32;
  const unsigned int Ri2u = RT2[(size_t)myi * NH + head];
  h2 Ri2; __builtin_memcpy(&Ri2, &Ri2u, 4);
  const uint4* bp4 = (const uint4*)(bits + (size_t)myi * (N / 32) + js * 32);

  // per-(head,js) fragment block: [c8*8+ss][lane][8 shorts]
  const unsigned short* gfrag =
      gT2 + (size_t)(head * NSPLIT + js) * 32768 + (size_t)lane * 8;

  frag_c16 acc = {0.f, 0.f, 0.f, 0.f, 0.f, 0.f, 0.f, 0.f,
                  0.f, 0.f, 0.f, 0.f, 0.f, 0.f, 0.f, 0.f};
  frag_c16 accl = {0.f, 0.f, 0.f, 0.f, 0.f, 0.f, 0.f, 0.f,
                   0.f, 0.f, 0.f, 0.f, 0.f, 0.f, 0.f, 0.f};
  frag_f16 fone;
#pragma unroll
  for (int u = 0; u < 8; ++u) fone[u] = (_Float16)1.0f;

  {  // stage B/D slab once (2 heads x 1024 fp16 x 2 planes = 8 KB)
    const int hsel = t >> 7, idx = t & 127;
    sBD[0][hsel][idx] =
        ((const uint4*)(BT + (size_t)(hp * 2 + hsel) * N + js * 1024))[idx];
    sBD[1][hsel][idx] =
        ((const uint4*)(DT + (size_t)(hp * 2 + hsel) * N + js * 1024))[idx];
  }
  __syncthreads();

  // chunk-0 fragment preload (registers) + bits word
  int4 bva[8];
#pragma unroll
  for (int ss = 0; ss < 8; ++ss)
    bva[ss] = *(const int4*)(gfrag + (size_t)ss * 512);
  uint4 bw = bp4[0];

  for (int c8 = 0; c8 < 8; ++c8) {
    int4 nba[8];
    uint4 bwn = bw;
    if (c8 < 7) {  // depth-1 register prefetch of next chunk (no barriers anywhere)
      bwn = bp4[c8 + 1];
#pragma unroll
      for (int ss = 0; ss < 8; ++ss)
        nba[ss] = *(const int4*)(gfrag + (size_t)((c8 + 1) * 8 + ss) * 512);
    }
    const unsigned int bwa[4] = {bw.x, bw.y, bw.z, bw.w};
#pragma unroll
    for (int half = 0; half < 2; ++half) {
      // batch-hoist this half's B/D broadcast reads (8 x ds_read_b128)
      uint4 Bva[4], Dva[4];
#pragma unroll
      for (int q = 0; q < 4; ++q) {
        const int ss = half * 4 + q;
        Bva[q] = sBD[0][hd][c8 * 16 + ss * 2 + kh];
        Dva[q] = sBD[1][hd][c8 * 16 + ss * 2 + kh];
      }
#pragma unroll
      for (int q = 0; q < 4; ++q) {
        const int ss = half * 4 + q;
        const unsigned int mb = (bwa[ss >> 1] >> (((ss & 1) << 4) + (kh << 3))) & 0xFFu;
        const unsigned int bu[4] = {Bva[q].x, Bva[q].y, Bva[q].z, Bva[q].w};
        const unsigned int du[4] = {Dva[q].x, Dva[q].y, Dva[q].z, Dva[q].w};
        unsigned int packed[4];
#pragma unroll
        for (int p = 0; p < 4; ++p) {
          h2 hB, hD;
          __builtin_memcpy(&hB, &bu[p], 4);
          __builtin_memcpy(&hD, &du[p], 4);
          const h2 wm = __builtin_elementwise_max(hB, Ri2 * hD);  // pk_mul + pk_max
          unsigned int wp; __builtin_memcpy(&wp, &wm, 4);
          const unsigned int d  = (mb >> (2 * p)) & 3u;
          const unsigned int sp = ((d | (d << 15)) & 0x10001u) * 0xFFFFu;
          wp &= sp;
          packed[p] = wp;
        }
        frag_f16 af; __builtin_memcpy(&af, packed, 16);
        frag_f16 bf; __builtin_memcpy(&bf, &bva[ss], 16);

        acc  = __builtin_amdgcn_mfma_f32_32x32x16_f16(af, bf, acc, 0, 0, 0);
        accl = __builtin_amdgcn_mfma_f32_32x32x16_f16(af, fone, accl, 0, 0, 0);
      }
    }
    if (c8 < 7) {
#pragma unroll
      for (int ss = 0; ss < 8; ++ss) bva[ss] = nba[ss];
      bw = bwn;
    }
  }

  // ---- epilogue: non-atomic per-js partial stores (wave owns its rows) ----
  float* op = parts + (size_t)js * N * F;
#pragma unroll
  for (int reg = 0; reg < 16; ++reg) {
    const int row = (reg & 3) + 8 * (reg >> 2) + 4 * kh;
    op[(size_t)(i0 + isub * 32 + row) * F + head * HID + n32] = acc[reg];
  }
  if (n32 == 0) {  // accl cols are identical; lane n32==0 stores l for its 8 rows
    float* lp = lparts + (size_t)js * N * NH;
#pragma unroll
    for (int reg = 0; reg < 16; ++reg) {
      const int row = (reg & 3) + 8 * (reg >> 2) + 4 * kh;
      lp[(size_t)(i0 + isub * 32 + row) * NH + head] = accl[reg];
    }
  }
}

// ================= K_NORM: sum partials + normalize =================
__global__ __launch_bounds__(256) void k_norm(const float* __restrict__ parts,
                                              const float* __restrict__ lparts,
                                              float* __restrict__ out) {
  const int idx = blockIdx.x * 256 + threadIdx.x;  // float4 index over N*F/4
  const int i = idx >> 6, fq = idx & 63;
  const int hh = fq >> 3;
  float l = 0.f;
  float4 v = make_float4(0.f, 0.f, 0.f, 0.f);
#pragma unroll
  for (int js = 0; js < NSPLIT; ++js) {
    l += lparts[(size_t)js * N * NH + (size_t)i * NH + hh];
    const float4 p = *(const float4*)(parts + (size_t)js * N * F + (size_t)idx * 4);
    v.x += p.x; v.y += p.y; v.z += p.z; v.w += p.w;
  }
  const float inv = 1.f / l;
  v.x *= inv; v.y *= inv; v.z *= inv; v.w *= inv;
  *(float4*)(out + (size_t)idx * 4) = v;
}

extern "C" void kernel_launch(void* const* d_in, const int* in_sizes, int n_in,
                              void* d_out, int out_size, void* d_ws, size_t ws_size,
                              hipStream_t stream) {
  const float* h   = (const float*)d_in[0];
  const float* W   = (const float*)d_in[1];
  const float* a   = (const float*)d_in[2];
  const int*   adj = (const int*)d_in[3];
  float* out = (float*)d_out;

  // workspace (~21 MB)
  char* ws = (char*)d_ws;
  unsigned short* gT2 = (unsigned short*)ws; ws += (size_t)N * F * 2;        // 2 MB
  unsigned int* bits = (unsigned int*)ws;    ws += (size_t)N * (N / 32) * 4; // 2 MB
  unsigned int* RT2 = (unsigned int*)ws;     ws += (size_t)N * NH * 4;
  unsigned short* BT = (unsigned short*)ws;  ws += (size_t)N * NH * 2;
  unsigned short* DT = (unsigned short*)ws;  ws += (size_t)N * NH * 2;
  float* U    = (float*)ws;                  ws += 16 * F * 4;
  float* parts  = (float*)ws;                ws += (size_t)NSPLIT * N * F * 4;  // 16 MB
  float* lparts = (float*)ws;                ws += (size_t)NSPLIT * N * NH * 4; // 512 KB

  k_u<<<dim3(16), dim3(256), 0, stream>>>(W, a, U);
  // MEASUREMENT ROUND: k_front launched twice (idempotent).
  // dur(k_front) = wall - 150.3us; dispatches should surface in top-5 w/ counters.
  k_front<<<dim3(2560), dim3(256), 0, stream>>>(h, W, U, adj, RT2, BT, DT, gT2, bits);
  k_front<<<dim3(2560), dim3(256), 0, stream>>>(h, W, U, adj, RT2, BT, DT, gT2, bits);
  k_agg<<<dim3((N / TI) * 4 * NSPLIT), dim3(256), 0, stream>>>(
      gT2, RT2, BT, DT, bits, parts, lparts);
  k_norm<<<dim3(N * F / 4 / 256), dim3(256), 0, stream>>>(parts, lparts, out);
}

// Round 13
// 164.361 us; speedup vs baseline: 1.0978x; 1.0978x over previous
//
#include <hip/hip_runtime.h>
#include <math.h>

constexpr int N   = 4096;   // nodes
constexpr int F   = 256;    // IN_FEAT (= NH*HID)
constexpr int NH  = 8;      // heads
constexpr int HID = 32;     // hidden per head
constexpr float SLOPE = 0.2f;

using h2       = __attribute__((ext_vector_type(2))) _Float16;
using frag_f16 = __attribute__((ext_vector_type(8))) _Float16;  // 4 VGPRs
using frag_cd  = __attribute__((ext_vector_type(4))) float;
using frag_c16 = __attribute__((ext_vector_type(16))) float;

__device__ inline unsigned short f2h(float x) {
  _Float16 v = (_Float16)x;
  unsigned short u; __builtin_memcpy(&u, &v, 2); return u;
}

// ================= K_U: U[c][k] = sum_f W[head*32+f][k] * a[side*32+f] =================
__global__ __launch_bounds__(256) void k_u(const float* __restrict__ W,
                                           const float* __restrict__ a,
                                           float* __restrict__ U) {
  const int c = blockIdx.x, k = threadIdx.x;
  const int head = c & 7, side = c >> 3;
  float acc = 0.f;
#pragma unroll
  for (int f = 0; f < 32; ++f)
    acc += W[(size_t)(head * 32 + f) * F + k] * a[side * 32 + f];
  U[c * F + k] = acc;
}

// ================= K_FRONT: everything before aggregation (ZERO LDS) =================
// INTERLEAVED personas by b%10 (8 bits : 1 s : 1 gemm) so the HBM-bound bits
// stream runs from t=0 with the latency-bound s/gemm blocks hiding under it
// (measured R12: k_front=30us vs ~15us overlap-perfect; R3: personas ADD).
//   role 0..7: adjacency bitmask via __ballot (64 MB adj stream)
//   role 8:    s = h@U -> RT2, BT, DT
//   role 9:    gT2 = (h @ W^T)^T fp16 via MFMA, fragment-order store
__global__ __launch_bounds__(256) void k_front(const float* __restrict__ h,
                                               const float* __restrict__ W,
                                               const float* __restrict__ U,
                                               const int* __restrict__ adj,
                                               unsigned int* __restrict__ RT2,
                                               unsigned short* __restrict__ BT,
                                               unsigned short* __restrict__ DT,
                                               unsigned short* __restrict__ gT2,
                                               unsigned int* __restrict__ bits) {
  const int b = blockIdx.x, t = threadIdx.x;
  const int role = b % 10, group = b / 10;   // 256 groups of 10
  if (role == 8) {
    // ---- s-part: thread (r,c); h-row reads broadcast across the 16 c-threads ----
    const int i0 = group * 16;
    const int r = t >> 4, c = t & 15;
    const float4* hp = (const float4*)(h + (size_t)(i0 + r) * F);
    const float4* up = (const float4*)(U + (size_t)c * F);
    float acc = 0.f;
#pragma unroll
    for (int k4 = 0; k4 < 64; ++k4) {
      const float4 hv = hp[k4];
      const float4 uv = up[k4];
      acc += hv.x * uv.x + hv.y * uv.y + hv.z * uv.z + hv.w * uv.w;
    }
    const int n = i0 + r;
    if (c < 8) {
      const unsigned int r16 = f2h(__expf(-0.8f * acc));
      RT2[(size_t)n * NH + c] = (r16 << 16) | r16;
    } else {
      const int hd = c - 8;
      BT[(size_t)hd * N + n] = f2h(__expf(acc));
      DT[(size_t)hd * N + n] = f2h(__expf(SLOPE * acc));
    }
  } else if (role == 9) {
    // ---- gT2 GEMM: one wave per 16x64 strip (1 mt x 4 nt), A reused 4x ----
    const int lane = t & 63;
    const int tile = group * 4 + (t >> 6);   // 0..1023
    const int mt = tile >> 2, nt4 = tile & 3;
    const int m0 = mt * 16, n0 = nt4 * 64;
    const int n16 = lane & 15, quad = lane >> 4;
    frag_cd acc[4];
#pragma unroll
    for (int j = 0; j < 4; ++j) acc[j] = frag_cd{0.f, 0.f, 0.f, 0.f};
    const float* ap = h + (size_t)(m0 + n16) * F + quad * 8;
    const float* bp = W + (size_t)(n0 + n16) * F + quad * 8;
#pragma unroll
    for (int ks = 0; ks < F / 32; ++ks) {
      const float4 a0 = *(const float4*)(ap + ks * 32);
      const float4 a1 = *(const float4*)(ap + ks * 32 + 4);
      const frag_f16 af = {(_Float16)a0.x, (_Float16)a0.y, (_Float16)a0.z, (_Float16)a0.w,
                           (_Float16)a1.x, (_Float16)a1.y, (_Float16)a1.z, (_Float16)a1.w};
#pragma unroll
      for (int j = 0; j < 4; ++j) {
        const float4 b0 = *(const float4*)(bp + (size_t)j * 16 * F + ks * 32);
        const float4 b1 = *(const float4*)(bp + (size_t)j * 16 * F + ks * 32 + 4);
        const frag_f16 bf = {(_Float16)b0.x, (_Float16)b0.y, (_Float16)b0.z, (_Float16)b0.w,
                             (_Float16)b1.x, (_Float16)b1.y, (_Float16)b1.z, (_Float16)b1.w};
        acc[j] = __builtin_amdgcn_mfma_f32_16x16x32_f16(af, bf, acc[j], 0, 0, 0);
      }
    }
    // fragment-order stores: (feature r, node m) -> gT2[head][js][c8][ss][kh*32+n32][e]
    const int m  = m0 + quad * 4;
    const int js_ = m >> 10, c8_ = (m >> 7) & 7, ss_ = (m >> 4) & 7;
    const int kh_ = (m >> 3) & 1, e_ = m & 7;  // e_ in {0,4}
#pragma unroll
    for (int j = 0; j < 4; ++j) {
      unsigned short tmp[4];
#pragma unroll
      for (int reg = 0; reg < 4; ++reg) tmp[reg] = f2h(acc[j][reg]);
      const int r = n0 + j * 16 + n16;         // feature row
      const int head_ = r >> 5, n32_ = r & 31;
      unsigned short* dst = gT2 + ((size_t)(head_ * 4 + js_) * 64 + (c8_ * 8 + ss_)) * 512
                                + (kh_ * 32 + n32_) * 8 + e_;
      *(int2*)dst = *(int2*)tmp;
    }
  } else {
    // ---- bitmask via ballot: lane l tests adj[base + q*64 + l]; one v_cmp
    // yields 64 bits (2 output words). Word w bit j = adj[row, w*32+j].
    const int lane = t & 63;
    const int wv   = t >> 6;
    const int bb   = group * 8 + role;       // bits-block index 0..2047
    const int row  = bb * 2 + (wv >> 1);
    const int half = wv & 1;  // each wave covers 2048 ints = 8 KB
    const int* src = adj + (size_t)row * N + half * 2048 + lane;
    unsigned int* dstw = bits + (size_t)row * (N / 32) + half * 64;
#pragma unroll
    for (int it = 0; it < 8; ++it) {
      const int v0 = src[it * 256];
      const int v1 = src[it * 256 + 64];
      const int v2 = src[it * 256 + 128];
      const int v3 = src[it * 256 + 192];
      const unsigned long long m0 = __ballot(v0 & 1);
      const unsigned long long m1 = __ballot(v1 & 1);
      const unsigned long long m2 = __ballot(v2 & 1);
      const unsigned long long m3 = __ballot(v3 & 1);
      if (lane < 8) {
        const unsigned long long ms = (lane & 4) ? ((lane & 2) ? m3 : m2)
                                                 : ((lane & 2) ? m1 : m0);
        const unsigned int w = (unsigned int)(ms >> ((lane & 1) * 32));
        dstw[it * 8 + lane] = w;
      }
    }
  }
}

// ================= K_AGG: 64i-tile 32x32 fp16-MFMA flash aggregation =================
// (unchanged; measured 24.3us in R11 — near its memory floor)
constexpr int TI = 64;
constexpr int NSPLIT = 4;

__global__ __launch_bounds__(256, 4) void k_agg(
    const unsigned short* __restrict__ gT2,
    const unsigned int* __restrict__ RT2,
    const unsigned short* __restrict__ BT, const unsigned short* __restrict__ DT,
    const unsigned int* __restrict__ bits,
    float* __restrict__ parts, float* __restrict__ lparts) {
  __shared__ __align__(16) uint4 sBD[2][2][128];         // [B/D][head][1024 fp16]

  const int t    = threadIdx.x;
  const int lane = t & 63;
  const int wv   = t >> 6;
  const int isub = wv & 1;
  const int hd   = wv >> 1;
  const int b    = blockIdx.x;
  const int hp   = b & 3;
  const int js   = (b >> 2) & (NSPLIT - 1);
  const int i0   = (b >> 4) * TI;
  const int head = hp * 2 + hd;

  const int n32 = lane & 31;
  const int kh  = lane >> 5;

  const int myi = i0 + isub * 32 + n32;
  const unsigned int Ri2u = RT2[(size_t)myi * NH + head];
  h2 Ri2; __builtin_memcpy(&Ri2, &Ri2u, 4);
  const uint4* bp4 = (const uint4*)(bits + (size_t)myi * (N / 32) + js * 32);

  // per-(head,js) fragment block: [c8*8+ss][lane][8 shorts]
  const unsigned short* gfrag =
      gT2 + (size_t)(head * NSPLIT + js) * 32768 + (size_t)lane * 8;

  frag_c16 acc = {0.f, 0.f, 0.f, 0.f, 0.f, 0.f, 0.f, 0.f,
                  0.f, 0.f, 0.f, 0.f, 0.f, 0.f, 0.f, 0.f};
  frag_c16 accl = {0.f, 0.f, 0.f, 0.f, 0.f, 0.f, 0.f, 0.f,
                   0.f, 0.f, 0.f, 0.f, 0.f, 0.f, 0.f, 0.f};
  frag_f16 fone;
#pragma unroll
  for (int u = 0; u < 8; ++u) fone[u] = (_Float16)1.0f;

  {  // stage B/D slab once (2 heads x 1024 fp16 x 2 planes = 8 KB)
    const int hsel = t >> 7, idx = t & 127;
    sBD[0][hsel][idx] =
        ((const uint4*)(BT + (size_t)(hp * 2 + hsel) * N + js * 1024))[idx];
    sBD[1][hsel][idx] =
        ((const uint4*)(DT + (size_t)(hp * 2 + hsel) * N + js * 1024))[idx];
  }
  __syncthreads();

  // chunk-0 fragment preload (registers) + bits word
  int4 bva[8];
#pragma unroll
  for (int ss = 0; ss < 8; ++ss)
    bva[ss] = *(const int4*)(gfrag + (size_t)ss * 512);
  uint4 bw = bp4[0];

  for (int c8 = 0; c8 < 8; ++c8) {
    int4 nba[8];
    uint4 bwn = bw;
    if (c8 < 7) {  // depth-1 register prefetch of next chunk (no barriers anywhere)
      bwn = bp4[c8 + 1];
#pragma unroll
      for (int ss = 0; ss < 8; ++ss)
        nba[ss] = *(const int4*)(gfrag + (size_t)((c8 + 1) * 8 + ss) * 512);
    }
    const unsigned int bwa[4] = {bw.x, bw.y, bw.z, bw.w};
#pragma unroll
    for (int half = 0; half < 2; ++half) {
      // batch-hoist this half's B/D broadcast reads (8 x ds_read_b128)
      uint4 Bva[4], Dva[4];
#pragma unroll
      for (int q = 0; q < 4; ++q) {
        const int ss = half * 4 + q;
        Bva[q] = sBD[0][hd][c8 * 16 + ss * 2 + kh];
        Dva[q] = sBD[1][hd][c8 * 16 + ss * 2 + kh];
      }
#pragma unroll
      for (int q = 0; q < 4; ++q) {
        const int ss = half * 4 + q;
        const unsigned int mb = (bwa[ss >> 1] >> (((ss & 1) << 4) + (kh << 3))) & 0xFFu;
        const unsigned int bu[4] = {Bva[q].x, Bva[q].y, Bva[q].z, Bva[q].w};
        const unsigned int du[4] = {Dva[q].x, Dva[q].y, Dva[q].z, Dva[q].w};
        unsigned int packed[4];
#pragma unroll
        for (int p = 0; p < 4; ++p) {
          h2 hB, hD;
          __builtin_memcpy(&hB, &bu[p], 4);
          __builtin_memcpy(&hD, &du[p], 4);
          const h2 wm = __builtin_elementwise_max(hB, Ri2 * hD);  // pk_mul + pk_max
          unsigned int wp; __builtin_memcpy(&wp, &wm, 4);
          const unsigned int d  = (mb >> (2 * p)) & 3u;
          const unsigned int sp = ((d | (d << 15)) & 0x10001u) * 0xFFFFu;
          wp &= sp;
          packed[p] = wp;
        }
        frag_f16 af; __builtin_memcpy(&af, packed, 16);
        frag_f16 bf; __builtin_memcpy(&bf, &bva[ss], 16);

        acc  = __builtin_amdgcn_mfma_f32_32x32x16_f16(af, bf, acc, 0, 0, 0);
        accl = __builtin_amdgcn_mfma_f32_32x32x16_f16(af, fone, accl, 0, 0, 0);
      }
    }
    if (c8 < 7) {
#pragma unroll
      for (int ss = 0; ss < 8; ++ss) bva[ss] = nba[ss];
      bw = bwn;
    }
  }

  // ---- epilogue: non-atomic per-js partial stores (wave owns its rows) ----
  float* op = parts + (size_t)js * N * F;
#pragma unroll
  for (int reg = 0; reg < 16; ++reg) {
    const int row = (reg & 3) + 8 * (reg >> 2) + 4 * kh;
    op[(size_t)(i0 + isub * 32 + row) * F + head * HID + n32] = acc[reg];
  }
  if (n32 == 0) {  // accl cols are identical; lane n32==0 stores l for its 8 rows
    float* lp = lparts + (size_t)js * N * NH;
#pragma unroll
    for (int reg = 0; reg < 16; ++reg) {
      const int row = (reg & 3) + 8 * (reg >> 2) + 4 * kh;
      lp[(size_t)(i0 + isub * 32 + row) * NH + head] = accl[reg];
    }
  }
}

// ================= K_NORM: sum partials + normalize =================
__global__ __launch_bounds__(256) void k_norm(const float* __restrict__ parts,
                                              const float* __restrict__ lparts,
                                              float* __restrict__ out) {
  const int idx = blockIdx.x * 256 + threadIdx.x;  // float4 index over N*F/4
  const int i = idx >> 6, fq = idx & 63;
  const int hh = fq >> 3;
  float l = 0.f;
  float4 v = make_float4(0.f, 0.f, 0.f, 0.f);
#pragma unroll
  for (int js = 0; js < NSPLIT; ++js) {
    l += lparts[(size_t)js * N * NH + (size_t)i * NH + hh];
    const float4 p = *(const float4*)(parts + (size_t)js * N * F + (size_t)idx * 4);
    v.x += p.x; v.y += p.y; v.z += p.z; v.w += p.w;
  }
  const float inv = 1.f / l;
  v.x *= inv; v.y *= inv; v.z *= inv; v.w *= inv;
  *(float4*)(out + (size_t)idx * 4) = v;
}

extern "C" void kernel_launch(void* const* d_in, const int* in_sizes, int n_in,
                              void* d_out, int out_size, void* d_ws, size_t ws_size,
                              hipStream_t stream) {
  const float* h   = (const float*)d_in[0];
  const float* W   = (const float*)d_in[1];
  const float* a   = (const float*)d_in[2];
  const int*   adj = (const int*)d_in[3];
  float* out = (float*)d_out;

  // workspace (~21 MB)
  char* ws = (char*)d_ws;
  unsigned short* gT2 = (unsigned short*)ws; ws += (size_t)N * F * 2;        // 2 MB
  unsigned int* bits = (unsigned int*)ws;    ws += (size_t)N * (N / 32) * 4; // 2 MB
  unsigned int* RT2 = (unsigned int*)ws;     ws += (size_t)N * NH * 4;
  unsigned short* BT = (unsigned short*)ws;  ws += (size_t)N * NH * 2;
  unsigned short* DT = (unsigned short*)ws;  ws += (size_t)N * NH * 2;
  float* U    = (float*)ws;                  ws += 16 * F * 4;
  float* parts  = (float*)ws;                ws += (size_t)NSPLIT * N * F * 4;  // 16 MB
  float* lparts = (float*)ws;                ws += (size_t)NSPLIT * N * NH * 4; // 512 KB

  k_u<<<dim3(16), dim3(256), 0, stream>>>(W, a, U);
  k_front<<<dim3(2560), dim3(256), 0, stream>>>(h, W, U, adj, RT2, BT, DT, gT2, bits);
  k_agg<<<dim3((N / TI) * 4 * NSPLIT), dim3(256), 0, stream>>>(
      gT2, RT2, BT, DT, bits, parts, lparts);
  k_norm<<<dim3(N * F / 4 / 256), dim3(256), 0, stream>>>(parts, lparts, out);
}

// Round 14
// 150.564 us; speedup vs baseline: 1.1984x; 1.0916x over previous
//
#include <hip/hip_runtime.h>
#include <math.h>

constexpr int N   = 4096;   // nodes
constexpr int F   = 256;    // IN_FEAT (= NH*HID)
constexpr int NH  = 8;      // heads
constexpr int HID = 32;     // hidden per head
constexpr float SLOPE = 0.2f;

using h2       = __attribute__((ext_vector_type(2))) _Float16;
using frag_f16 = __attribute__((ext_vector_type(8))) _Float16;  // 4 VGPRs
using frag_cd  = __attribute__((ext_vector_type(4))) float;
using frag_c16 = __attribute__((ext_vector_type(16))) float;

__device__ inline unsigned short f2h(float x) {
  _Float16 v = (_Float16)x;
  unsigned short u; __builtin_memcpy(&u, &v, 2); return u;
}

// ================= K_U: U[c][k] = sum_f W[head*32+f][k] * a[side*32+f] =================
__global__ __launch_bounds__(256) void k_u(const float* __restrict__ W,
                                           const float* __restrict__ a,
                                           float* __restrict__ U) {
  const int c = blockIdx.x, k = threadIdx.x;
  const int head = c & 7, side = c >> 3;
  float acc = 0.f;
#pragma unroll
  for (int f = 0; f < 32; ++f)
    acc += W[(size_t)(head * 32 + f) * F + k] * a[side * 32 + f];
  U[c * F + k] = acc;
}

// ================= K_FRONT: everything before aggregation (ZERO LDS) =================
// Block-range personas (R13 interleave REGRESSED 30->53us; this layout = 30us):
// [0,256):    s = h@U (U from global, L1-hot) -> RT2, BT, DT
// [256,512):  gT2 = (h @ W^T)^T fp16 via MFMA, 1 mt x 4 nt per wave (A reused 4x),
//             stored in MFMA-FRAGMENT ORDER: gT2[head][js][c8][ss][kh*32+n32][8].
// [512,2560): adjacency bitmask via __ballot (adj is mostly L3-resident, R13 FETCH).
__global__ __launch_bounds__(256) void k_front(const float* __restrict__ h,
                                               const float* __restrict__ W,
                                               const float* __restrict__ U,
                                               const int* __restrict__ adj,
                                               unsigned int* __restrict__ RT2,
                                               unsigned short* __restrict__ BT,
                                               unsigned short* __restrict__ DT,
                                               unsigned short* __restrict__ gT2,
                                               unsigned int* __restrict__ bits) {
  const int b = blockIdx.x, t = threadIdx.x;
  if (b < 256) {
    // ---- s-part: thread (r,c); h-row reads broadcast across the 16 c-threads ----
    const int i0 = b * 16;
    const int r = t >> 4, c = t & 15;
    const float4* hp = (const float4*)(h + (size_t)(i0 + r) * F);
    const float4* up = (const float4*)(U + (size_t)c * F);
    float acc = 0.f;
#pragma unroll
    for (int k4 = 0; k4 < 64; ++k4) {
      const float4 hv = hp[k4];
      const float4 uv = up[k4];
      acc += hv.x * uv.x + hv.y * uv.y + hv.z * uv.z + hv.w * uv.w;
    }
    const int n = i0 + r;
    if (c < 8) {
      const unsigned int r16 = f2h(__expf(-0.8f * acc));
      RT2[(size_t)n * NH + c] = (r16 << 16) | r16;
    } else {
      const int hd = c - 8;
      BT[(size_t)hd * N + n] = f2h(__expf(acc));
      DT[(size_t)hd * N + n] = f2h(__expf(SLOPE * acc));
    }
  } else if (b < 512) {
    // ---- gT2 GEMM: one wave per 16x64 strip (1 mt x 4 nt), A reused 4x ----
    const int lane = t & 63;
    const int tile = (b - 256) * 4 + (t >> 6);   // 0..1023
    const int mt = tile >> 2, nt4 = tile & 3;
    const int m0 = mt * 16, n0 = nt4 * 64;
    const int n16 = lane & 15, quad = lane >> 4;
    frag_cd acc[4];
#pragma unroll
    for (int j = 0; j < 4; ++j) acc[j] = frag_cd{0.f, 0.f, 0.f, 0.f};
    const float* ap = h + (size_t)(m0 + n16) * F + quad * 8;
    const float* bp = W + (size_t)(n0 + n16) * F + quad * 8;
#pragma unroll
    for (int ks = 0; ks < F / 32; ++ks) {
      const float4 a0 = *(const float4*)(ap + ks * 32);
      const float4 a1 = *(const float4*)(ap + ks * 32 + 4);
      const frag_f16 af = {(_Float16)a0.x, (_Float16)a0.y, (_Float16)a0.z, (_Float16)a0.w,
                           (_Float16)a1.x, (_Float16)a1.y, (_Float16)a1.z, (_Float16)a1.w};
#pragma unroll
      for (int j = 0; j < 4; ++j) {
        const float4 b0 = *(const float4*)(bp + (size_t)j * 16 * F + ks * 32);
        const float4 b1 = *(const float4*)(bp + (size_t)j * 16 * F + ks * 32 + 4);
        const frag_f16 bf = {(_Float16)b0.x, (_Float16)b0.y, (_Float16)b0.z, (_Float16)b0.w,
                             (_Float16)b1.x, (_Float16)b1.y, (_Float16)b1.z, (_Float16)b1.w};
        acc[j] = __builtin_amdgcn_mfma_f32_16x16x32_f16(af, bf, acc[j], 0, 0, 0);
      }
    }
    // fragment-order stores: (feature r, node m) -> gT2[head][js][c8][ss][kh*32+n32][e]
    const int m  = m0 + quad * 4;
    const int js_ = m >> 10, c8_ = (m >> 7) & 7, ss_ = (m >> 4) & 7;
    const int kh_ = (m >> 3) & 1, e_ = m & 7;  // e_ in {0,4}
#pragma unroll
    for (int j = 0; j < 4; ++j) {
      unsigned short tmp[4];
#pragma unroll
      for (int reg = 0; reg < 4; ++reg) tmp[reg] = f2h(acc[j][reg]);
      const int r = n0 + j * 16 + n16;         // feature row
      const int head_ = r >> 5, n32_ = r & 31;
      unsigned short* dst = gT2 + ((size_t)(head_ * 4 + js_) * 64 + (c8_ * 8 + ss_)) * 512
                                + (kh_ * 32 + n32_) * 8 + e_;
      *(int2*)dst = *(int2*)tmp;
    }
  } else {
    // ---- bitmask via ballot: lane l tests adj[base + q*64 + l]; one v_cmp
    // yields 64 bits (2 output words). Word w bit j = adj[row, w*32+j].
    const int lane = t & 63;
    const int wv   = t >> 6;
    const int row  = (b - 512) * 2 + (wv >> 1);
    const int half = wv & 1;  // each wave covers 2048 ints = 8 KB
    const int* src = adj + (size_t)row * N + half * 2048 + lane;
    unsigned int* dstw = bits + (size_t)row * (N / 32) + half * 64;
#pragma unroll
    for (int it = 0; it < 8; ++it) {
      const int v0 = src[it * 256];
      const int v1 = src[it * 256 + 64];
      const int v2 = src[it * 256 + 128];
      const int v3 = src[it * 256 + 192];
      const unsigned long long m0 = __ballot(v0 & 1);
      const unsigned long long m1 = __ballot(v1 & 1);
      const unsigned long long m2 = __ballot(v2 & 1);
      const unsigned long long m3 = __ballot(v3 & 1);
      if (lane < 8) {
        const unsigned long long ms = (lane & 4) ? ((lane & 2) ? m3 : m2)
                                                 : ((lane & 2) ? m1 : m0);
        const unsigned int w = (unsigned int)(ms >> ((lane & 1) * 32));
        dstw[it * 8 + lane] = w;
      }
    }
  }
}

// ================= K_AGG: 128i-tile 32x32 fp16-MFMA flash aggregation =================
// TI=128: 512-thread blocks, 8 waves (isub = wv&3 covers 128 i-rows, hd = wv>>2).
// Halves per-L2 gT2 fragment traffic (1024->512 blocks x 128 KB distinct each)
// with identical waves/CU (2 blocks x 8 waves = 16). Barrier-free main loop.
constexpr int TI = 128;
constexpr int NSPLIT = 4;

__global__ __launch_bounds__(512, 4) void k_agg(
    const unsigned short* __restrict__ gT2,
    const unsigned int* __restrict__ RT2,
    const unsigned short* __restrict__ BT, const unsigned short* __restrict__ DT,
    const unsigned int* __restrict__ bits,
    float* __restrict__ parts, float* __restrict__ lparts) {
  __shared__ __align__(16) uint4 sBD[2][2][128];         // [B/D][head][1024 fp16]

  const int t    = threadIdx.x;
  const int lane = t & 63;
  const int wv   = t >> 6;
  const int isub = wv & 3;
  const int hd   = wv >> 2;
  const int b    = blockIdx.x;
  const int hp   = b & 3;
  const int js   = (b >> 2) & (NSPLIT - 1);
  const int i0   = (b >> 4) * TI;
  const int head = hp * 2 + hd;

  const int n32 = lane & 31;
  const int kh  = lane >> 5;

  const int myi = i0 + isub * 32 + n32;
  const unsigned int Ri2u = RT2[(size_t)myi * NH + head];
  h2 Ri2; __builtin_memcpy(&Ri2, &Ri2u, 4);
  const uint4* bp4 = (const uint4*)(bits + (size_t)myi * (N / 32) + js * 32);

  // per-(head,js) fragment block: [c8*8+ss][lane][8 shorts]
  const unsigned short* gfrag =
      gT2 + (size_t)(head * NSPLIT + js) * 32768 + (size_t)lane * 8;

  frag_c16 acc = {0.f, 0.f, 0.f, 0.f, 0.f, 0.f, 0.f, 0.f,
                  0.f, 0.f, 0.f, 0.f, 0.f, 0.f, 0.f, 0.f};
  frag_c16 accl = {0.f, 0.f, 0.f, 0.f, 0.f, 0.f, 0.f, 0.f,
                   0.f, 0.f, 0.f, 0.f, 0.f, 0.f, 0.f, 0.f};
  frag_f16 fone;
#pragma unroll
  for (int u = 0; u < 8; ++u) fone[u] = (_Float16)1.0f;

  {  // stage B/D slab once (2 heads x 1024 fp16 x 2 planes = 8 KB); t < 256
    if (t < 256) {
      const int hsel = t >> 7, idx = t & 127;
      sBD[0][hsel][idx] =
          ((const uint4*)(BT + (size_t)(hp * 2 + hsel) * N + js * 1024))[idx];
      sBD[1][hsel][idx] =
          ((const uint4*)(DT + (size_t)(hp * 2 + hsel) * N + js * 1024))[idx];
    }
  }
  __syncthreads();

  // chunk-0 fragment preload (registers) + bits word
  int4 bva[8];
#pragma unroll
  for (int ss = 0; ss < 8; ++ss)
    bva[ss] = *(const int4*)(gfrag + (size_t)ss * 512);
  uint4 bw = bp4[0];

  for (int c8 = 0; c8 < 8; ++c8) {
    int4 nba[8];
    uint4 bwn = bw;
    if (c8 < 7) {  // depth-1 register prefetch of next chunk (no barriers anywhere)
      bwn = bp4[c8 + 1];
#pragma unroll
      for (int ss = 0; ss < 8; ++ss)
        nba[ss] = *(const int4*)(gfrag + (size_t)((c8 + 1) * 8 + ss) * 512);
    }
    const unsigned int bwa[4] = {bw.x, bw.y, bw.z, bw.w};
#pragma unroll
    for (int half = 0; half < 2; ++half) {
      // batch-hoist this half's B/D broadcast reads (8 x ds_read_b128)
      uint4 Bva[4], Dva[4];
#pragma unroll
      for (int q = 0; q < 4; ++q) {
        const int ss = half * 4 + q;
        Bva[q] = sBD[0][hd][c8 * 16 + ss * 2 + kh];
        Dva[q] = sBD[1][hd][c8 * 16 + ss * 2 + kh];
      }
#pragma unroll
      for (int q = 0; q < 4; ++q) {
        const int ss = half * 4 + q;
        const unsigned int mb = (bwa[ss >> 1] >> (((ss & 1) << 4) + (kh << 3))) & 0xFFu;
        const unsigned int bu[4] = {Bva[q].x, Bva[q].y, Bva[q].z, Bva[q].w};
        const unsigned int du[4] = {Dva[q].x, Dva[q].y, Dva[q].z, Dva[q].w};
        unsigned int packed[4];
#pragma unroll
        for (int p = 0; p < 4; ++p) {
          h2 hB, hD;
          __builtin_memcpy(&hB, &bu[p], 4);
          __builtin_memcpy(&hD, &du[p], 4);
          const h2 wm = __builtin_elementwise_max(hB, Ri2 * hD);  // pk_mul + pk_max
          unsigned int wp; __builtin_memcpy(&wp, &wm, 4);
          const unsigned int d  = (mb >> (2 * p)) & 3u;
          const unsigned int sp = ((d | (d << 15)) & 0x10001u) * 0xFFFFu;
          wp &= sp;
          packed[p] = wp;
        }
        frag_f16 af; __builtin_memcpy(&af, packed, 16);
        frag_f16 bf; __builtin_memcpy(&bf, &bva[ss], 16);

        acc  = __builtin_amdgcn_mfma_f32_32x32x16_f16(af, bf, acc, 0, 0, 0);
        accl = __builtin_amdgcn_mfma_f32_32x32x16_f16(af, fone, accl, 0, 0, 0);
      }
    }
    if (c8 < 7) {
#pragma unroll
      for (int ss = 0; ss < 8; ++ss) bva[ss] = nba[ss];
      bw = bwn;
    }
  }

  // ---- epilogue: non-atomic per-js partial stores (wave owns its rows) ----
  float* op = parts + (size_t)js * N * F;
#pragma unroll
  for (int reg = 0; reg < 16; ++reg) {
    const int row = (reg & 3) + 8 * (reg >> 2) + 4 * kh;
    op[(size_t)(i0 + isub * 32 + row) * F + head * HID + n32] = acc[reg];
  }
  if (n32 == 0) {  // accl cols are identical; lane n32==0 stores l for its 8 rows
    float* lp = lparts + (size_t)js * N * NH;
#pragma unroll
    for (int reg = 0; reg < 16; ++reg) {
      const int row = (reg & 3) + 8 * (reg >> 2) + 4 * kh;
      lp[(size_t)(i0 + isub * 32 + row) * NH + head] = accl[reg];
    }
  }
}

// ================= K_NORM: sum partials + normalize =================
__global__ __launch_bounds__(256) void k_norm(const float* __restrict__ parts,
                                              const float* __restrict__ lparts,
                                              float* __restrict__ out) {
  const int idx = blockIdx.x * 256 + threadIdx.x;  // float4 index over N*F/4
  const int i = idx >> 6, fq = idx & 63;
  const int hh = fq >> 3;
  float l = 0.f;
  float4 v = make_float4(0.f, 0.f, 0.f, 0.f);
#pragma unroll
  for (int js = 0; js < NSPLIT; ++js) {
    l += lparts[(size_t)js * N * NH + (size_t)i * NH + hh];
    const float4 p = *(const float4*)(parts + (size_t)js * N * F + (size_t)idx * 4);
    v.x += p.x; v.y += p.y; v.z += p.z; v.w += p.w;
  }
  const float inv = 1.f / l;
  v.x *= inv; v.y *= inv; v.z *= inv; v.w *= inv;
  *(float4*)(out + (size_t)idx * 4) = v;
}

extern "C" void kernel_launch(void* const* d_in, const int* in_sizes, int n_in,
                              void* d_out, int out_size, void* d_ws, size_t ws_size,
                              hipStream_t stream) {
  const float* h   = (const float*)d_in[0];
  const float* W   = (const float*)d_in[1];
  const float* a   = (const float*)d_in[2];
  const int*   adj = (const int*)d_in[3];
  float* out = (float*)d_out;

  // workspace (~21 MB)
  char* ws = (char*)d_ws;
  unsigned short* gT2 = (unsigned short*)ws; ws += (size_t)N * F * 2;        // 2 MB
  unsigned int* bits = (unsigned int*)ws;    ws += (size_t)N * (N / 32) * 4; // 2 MB
  unsigned int* RT2 = (unsigned int*)ws;     ws += (size_t)N * NH * 4;
  unsigned short* BT = (unsigned short*)ws;  ws += (size_t)N * NH * 2;
  unsigned short* DT = (unsigned short*)ws;  ws += (size_t)N * NH * 2;
  float* U    = (float*)ws;                  ws += 16 * F * 4;
  float* parts  = (float*)ws;                ws += (size_t)NSPLIT * N * F * 4;  // 16 MB
  float* lparts = (float*)ws;                ws += (size_t)NSPLIT * N * NH * 4; // 512 KB

  k_u<<<dim3(16), dim3(256), 0, stream>>>(W, a, U);
  k_front<<<dim3(2560), dim3(256), 0, stream>>>(h, W, U, adj, RT2, BT, DT, gT2, bits);
  k_agg<<<dim3((N / TI) * 4 * NSPLIT), dim3(512), 0, stream>>>(
      gT2, RT2, BT, DT, bits, parts, lparts);
  k_norm<<<dim3(N * F / 4 / 256), dim3(256), 0, stream>>>(parts, lparts, out);
}

// Round 15
// 148.606 us; speedup vs baseline: 1.2141x; 1.0132x over previous
//
#include <hip/hip_runtime.h>
#include <math.h>

constexpr int N   = 4096;   // nodes
constexpr int F   = 256;    // IN_FEAT (= NH*HID)
constexpr int NH  = 8;      // heads
constexpr int HID = 32;     // hidden per head
constexpr float SLOPE = 0.2f;

using h2       = __attribute__((ext_vector_type(2))) _Float16;
using frag_f16 = __attribute__((ext_vector_type(8))) _Float16;  // 4 VGPRs
using frag_cd  = __attribute__((ext_vector_type(4))) float;
using frag_c16 = __attribute__((ext_vector_type(16))) float;

__device__ inline unsigned short f2h(float x) {
  _Float16 v = (_Float16)x;
  unsigned short u; __builtin_memcpy(&u, &v, 2); return u;
}

// ================= K_U: U[c][k] = sum_f W[head*32+f][k] * a[side*32+f] =================
__global__ __launch_bounds__(256) void k_u(const float* __restrict__ W,
                                           const float* __restrict__ a,
                                           float* __restrict__ U) {
  const int c = blockIdx.x, k = threadIdx.x;
  const int head = c & 7, side = c >> 3;
  float acc = 0.f;
#pragma unroll
  for (int f = 0; f < 32; ++f)
    acc += W[(size_t)(head * 32 + f) * F + k] * a[side * 32 + f];
  U[c * F + k] = acc;
}

// ================= K_FRONT: everything before aggregation (ZERO LDS) =================
// Block-range personas (R13 interleave REGRESSED; this layout = measured 30us):
// [0,256):    s = h@U (U from global, L1-hot) -> RT2, BT, DT
// [256,512):  gT2 = (h @ W^T)^T fp16 via MFMA, 1 mt x 4 nt per wave (A reused 4x),
//             stored in MFMA-FRAGMENT ORDER: gT2[head][unit][c8][ss][kh*32+n32][8]
//             (unit = m>>10: four 1024-node units, independent of k_agg NSPLIT).
// [512,2560): adjacency bitmask via __ballot (adj mostly L3-resident, R13 FETCH).
__global__ __launch_bounds__(256) void k_front(const float* __restrict__ h,
                                               const float* __restrict__ W,
                                               const float* __restrict__ U,
                                               const int* __restrict__ adj,
                                               unsigned int* __restrict__ RT2,
                                               unsigned short* __restrict__ BT,
                                               unsigned short* __restrict__ DT,
                                               unsigned short* __restrict__ gT2,
                                               unsigned int* __restrict__ bits) {
  const int b = blockIdx.x, t = threadIdx.x;
  if (b < 256) {
    // ---- s-part: thread (r,c); h-row reads broadcast across the 16 c-threads ----
    const int i0 = b * 16;
    const int r = t >> 4, c = t & 15;
    const float4* hp = (const float4*)(h + (size_t)(i0 + r) * F);
    const float4* up = (const float4*)(U + (size_t)c * F);
    float acc = 0.f;
#pragma unroll
    for (int k4 = 0; k4 < 64; ++k4) {
      const float4 hv = hp[k4];
      const float4 uv = up[k4];
      acc += hv.x * uv.x + hv.y * uv.y + hv.z * uv.z + hv.w * uv.w;
    }
    const int n = i0 + r;
    if (c < 8) {
      const unsigned int r16 = f2h(__expf(-0.8f * acc));
      RT2[(size_t)n * NH + c] = (r16 << 16) | r16;
    } else {
      const int hd = c - 8;
      BT[(size_t)hd * N + n] = f2h(__expf(acc));
      DT[(size_t)hd * N + n] = f2h(__expf(SLOPE * acc));
    }
  } else if (b < 512) {
    // ---- gT2 GEMM: one wave per 16x64 strip (1 mt x 4 nt), A reused 4x ----
    const int lane = t & 63;
    const int tile = (b - 256) * 4 + (t >> 6);   // 0..1023
    const int mt = tile >> 2, nt4 = tile & 3;
    const int m0 = mt * 16, n0 = nt4 * 64;
    const int n16 = lane & 15, quad = lane >> 4;
    frag_cd acc[4];
#pragma unroll
    for (int j = 0; j < 4; ++j) acc[j] = frag_cd{0.f, 0.f, 0.f, 0.f};
    const float* ap = h + (size_t)(m0 + n16) * F + quad * 8;
    const float* bp = W + (size_t)(n0 + n16) * F + quad * 8;
#pragma unroll
    for (int ks = 0; ks < F / 32; ++ks) {
      const float4 a0 = *(const float4*)(ap + ks * 32);
      const float4 a1 = *(const float4*)(ap + ks * 32 + 4);
      const frag_f16 af = {(_Float16)a0.x, (_Float16)a0.y, (_Float16)a0.z, (_Float16)a0.w,
                           (_Float16)a1.x, (_Float16)a1.y, (_Float16)a1.z, (_Float16)a1.w};
#pragma unroll
      for (int j = 0; j < 4; ++j) {
        const float4 b0 = *(const float4*)(bp + (size_t)j * 16 * F + ks * 32);
        const float4 b1 = *(const float4*)(bp + (size_t)j * 16 * F + ks * 32 + 4);
        const frag_f16 bf = {(_Float16)b0.x, (_Float16)b0.y, (_Float16)b0.z, (_Float16)b0.w,
                             (_Float16)b1.x, (_Float16)b1.y, (_Float16)b1.z, (_Float16)b1.w};
        acc[j] = __builtin_amdgcn_mfma_f32_16x16x32_f16(af, bf, acc[j], 0, 0, 0);
      }
    }
    // fragment-order stores: (feature r, node m) -> gT2[head][unit][c8][ss][kh*32+n32][e]
    const int m  = m0 + quad * 4;
    const int u_ = m >> 10, c8_ = (m >> 7) & 7, ss_ = (m >> 4) & 7;
    const int kh_ = (m >> 3) & 1, e_ = m & 7;  // e_ in {0,4}
#pragma unroll
    for (int j = 0; j < 4; ++j) {
      unsigned short tmp[4];
#pragma unroll
      for (int reg = 0; reg < 4; ++reg) tmp[reg] = f2h(acc[j][reg]);
      const int r = n0 + j * 16 + n16;         // feature row
      const int head_ = r >> 5, n32_ = r & 31;
      unsigned short* dst = gT2 + ((size_t)(head_ * 4 + u_) * 64 + (c8_ * 8 + ss_)) * 512
                                + (kh_ * 32 + n32_) * 8 + e_;
      *(int2*)dst = *(int2*)tmp;
    }
  } else {
    // ---- bitmask via ballot: lane l tests adj[base + q*64 + l]; one v_cmp
    // yields 64 bits (2 output words). Word w bit j = adj[row, w*32+j].
    const int lane = t & 63;
    const int wv   = t >> 6;
    const int row  = (b - 512) * 2 + (wv >> 1);
    const int half = wv & 1;  // each wave covers 2048 ints = 8 KB
    const int* src = adj + (size_t)row * N + half * 2048 + lane;
    unsigned int* dstw = bits + (size_t)row * (N / 32) + half * 64;
#pragma unroll
    for (int it = 0; it < 8; ++it) {
      const int v0 = src[it * 256];
      const int v1 = src[it * 256 + 64];
      const int v2 = src[it * 256 + 128];
      const int v3 = src[it * 256 + 192];
      const unsigned long long m0 = __ballot(v0 & 1);
      const unsigned long long m1 = __ballot(v1 & 1);
      const unsigned long long m2 = __ballot(v2 & 1);
      const unsigned long long m3 = __ballot(v3 & 1);
      if (lane < 8) {
        const unsigned long long ms = (lane & 4) ? ((lane & 2) ? m3 : m2)
                                                 : ((lane & 2) ? m1 : m0);
        const unsigned int w = (unsigned int)(ms >> ((lane & 1) * 32));
        dstw[it * 8 + lane] = w;
      }
    }
  }
}

// ================= K_AGG: 64i-tile 32x32 fp16-MFMA flash aggregation =================
// NSPLIT=2: each block covers 2048 j (16 chunks) -> half the blocks (512), half
// the prologues/epilogues/parts-traffic of NSPLIT=4. Barrier-free main loop,
// depth-1 register prefetch. gT2 layout unchanged: unit = js*2 + (c8>>3).
constexpr int TI = 64;
constexpr int NSPLIT = 2;

__global__ __launch_bounds__(256, 4) void k_agg(
    const unsigned short* __restrict__ gT2,
    const unsigned int* __restrict__ RT2,
    const unsigned short* __restrict__ BT, const unsigned short* __restrict__ DT,
    const unsigned int* __restrict__ bits,
    float* __restrict__ parts, float* __restrict__ lparts) {
  __shared__ __align__(16) uint4 sBD[2][2][256];         // [B/D][head][2048 fp16]

  const int t    = threadIdx.x;
  const int lane = t & 63;
  const int wv   = t >> 6;
  const int isub = wv & 1;
  const int hd   = wv >> 1;
  const int b    = blockIdx.x;
  const int hp   = b & 3;
  const int js   = (b >> 2) & (NSPLIT - 1);
  const int i0   = (b >> 3) * TI;
  const int head = hp * 2 + hd;

  const int n32 = lane & 31;
  const int kh  = lane >> 5;

  const int myi = i0 + isub * 32 + n32;
  const unsigned int Ri2u = RT2[(size_t)myi * NH + head];
  h2 Ri2; __builtin_memcpy(&Ri2, &Ri2u, 4);
  const uint4* bp4 = (const uint4*)(bits + (size_t)myi * (N / 32)) + js * 16;

  // per-head fragment base; chunk c8 (0..15) lives in unit js*2+(c8>>3)
  const unsigned short* gbase =
      gT2 + (size_t)(head * 4 + js * 2) * 32768 + (size_t)lane * 8;

  frag_c16 acc = {0.f, 0.f, 0.f, 0.f, 0.f, 0.f, 0.f, 0.f,
                  0.f, 0.f, 0.f, 0.f, 0.f, 0.f, 0.f, 0.f};
  frag_c16 accl = {0.f, 0.f, 0.f, 0.f, 0.f, 0.f, 0.f, 0.f,
                   0.f, 0.f, 0.f, 0.f, 0.f, 0.f, 0.f, 0.f};
  frag_f16 fone;
#pragma unroll
  for (int u = 0; u < 8; ++u) fone[u] = (_Float16)1.0f;

  {  // stage B/D slab once (2 heads x 2048 fp16 x 2 planes = 16 KB)
    const int hsel = t >> 7, idx = t & 127;
    const uint4* bsrc = (const uint4*)(BT + (size_t)(hp * 2 + hsel) * N + js * 2048);
    const uint4* dsrc = (const uint4*)(DT + (size_t)(hp * 2 + hsel) * N + js * 2048);
    sBD[0][hsel][idx]       = bsrc[idx];
    sBD[0][hsel][idx + 128] = bsrc[idx + 128];
    sBD[1][hsel][idx]       = dsrc[idx];
    sBD[1][hsel][idx + 128] = dsrc[idx + 128];
  }
  __syncthreads();

  // chunk-0 fragment preload (registers) + bits word
  int4 bva[8];
#pragma unroll
  for (int ss = 0; ss < 8; ++ss)
    bva[ss] = *(const int4*)(gbase + (size_t)ss * 512);
  uint4 bw = bp4[0];

  for (int c8 = 0; c8 < 16; ++c8) {
    int4 nba[8];
    uint4 bwn = bw;
    if (c8 < 15) {  // depth-1 register prefetch of next chunk (no barriers anywhere)
      bwn = bp4[c8 + 1];
      const unsigned short* gnext =
          gbase + (size_t)((c8 + 1) >> 3) * 32768 + (size_t)(((c8 + 1) & 7) * 8) * 512;
#pragma unroll
      for (int ss = 0; ss < 8; ++ss)
        nba[ss] = *(const int4*)(gnext + (size_t)ss * 512);
    }
    const unsigned int bwa[4] = {bw.x, bw.y, bw.z, bw.w};
#pragma unroll
    for (int half = 0; half < 2; ++half) {
      // batch-hoist this half's B/D broadcast reads (8 x ds_read_b128)
      uint4 Bva[4], Dva[4];
#pragma unroll
      for (int q = 0; q < 4; ++q) {
        const int ss = half * 4 + q;
        Bva[q] = sBD[0][hd][c8 * 16 + ss * 2 + kh];
        Dva[q] = sBD[1][hd][c8 * 16 + ss * 2 + kh];
      }
#pragma unroll
      for (int q = 0; q < 4; ++q) {
        const int ss = half * 4 + q;
        const unsigned int mb = (bwa[ss >> 1] >> (((ss & 1) << 4) + (kh << 3))) & 0xFFu;
        const unsigned int bu[4] = {Bva[q].x, Bva[q].y, Bva[q].z, Bva[q].w};
        const unsigned int du[4] = {Dva[q].x, Dva[q].y, Dva[q].z, Dva[q].w};
        unsigned int packed[4];
#pragma unroll
        for (int p = 0; p < 4; ++p) {
          h2 hB, hD;
          __builtin_memcpy(&hB, &bu[p], 4);
          __builtin_memcpy(&hD, &du[p], 4);
          const h2 wm = __builtin_elementwise_max(hB, Ri2 * hD);  // pk_mul + pk_max
          unsigned int wp; __builtin_memcpy(&wp, &wm, 4);
          const unsigned int d  = (mb >> (2 * p)) & 3u;
          const unsigned int sp = ((d | (d << 15)) & 0x10001u) * 0xFFFFu;
          wp &= sp;
          packed[p] = wp;
        }
        frag_f16 af; __builtin_memcpy(&af, packed, 16);
        frag_f16 bf; __builtin_memcpy(&bf, &bva[ss], 16);

        acc  = __builtin_amdgcn_mfma_f32_32x32x16_f16(af, bf, acc, 0, 0, 0);
        accl = __builtin_amdgcn_mfma_f32_32x32x16_f16(af, fone, accl, 0, 0, 0);
      }
    }
    if (c8 < 15) {
#pragma unroll
      for (int ss = 0; ss < 8; ++ss) bva[ss] = nba[ss];
      bw = bwn;
    }
  }

  // ---- epilogue: non-atomic per-js partial stores (wave owns its rows) ----
  float* op = parts + (size_t)js * N * F;
#pragma unroll
  for (int reg = 0; reg < 16; ++reg) {
    const int row = (reg & 3) + 8 * (reg >> 2) + 4 * kh;
    op[(size_t)(i0 + isub * 32 + row) * F + head * HID + n32] = acc[reg];
  }
  if (n32 == 0) {  // accl cols are identical; lane n32==0 stores l for its 8 rows
    float* lp = lparts + (size_t)js * N * NH;
#pragma unroll
    for (int reg = 0; reg < 16; ++reg) {
      const int row = (reg & 3) + 8 * (reg >> 2) + 4 * kh;
      lp[(size_t)(i0 + isub * 32 + row) * NH + head] = accl[reg];
    }
  }
}

// ================= K_NORM: sum partials + normalize =================
__global__ __launch_bounds__(256) void k_norm(const float* __restrict__ parts,
                                              const float* __restrict__ lparts,
                                              float* __restrict__ out) {
  const int idx = blockIdx.x * 256 + threadIdx.x;  // float4 index over N*F/4
  const int i = idx >> 6, fq = idx & 63;
  const int hh = fq >> 3;
  float l = 0.f;
  float4 v = make_float4(0.f, 0.f, 0.f, 0.f);
#pragma unroll
  for (int js = 0; js < NSPLIT; ++js) {
    l += lparts[(size_t)js * N * NH + (size_t)i * NH + hh];
    const float4 p = *(const float4*)(parts + (size_t)js * N * F + (size_t)idx * 4);
    v.x += p.x; v.y += p.y; v.z += p.z; v.w += p.w;
  }
  const float inv = 1.f / l;
  v.x *= inv; v.y *= inv; v.z *= inv; v.w *= inv;
  *(float4*)(out + (size_t)idx * 4) = v;
}

extern "C" void kernel_launch(void* const* d_in, const int* in_sizes, int n_in,
                              void* d_out, int out_size, void* d_ws, size_t ws_size,
                              hipStream_t stream) {
  const float* h   = (const float*)d_in[0];
  const float* W   = (const float*)d_in[1];
  const float* a   = (const float*)d_in[2];
  const int*   adj = (const int*)d_in[3];
  float* out = (float*)d_out;

  // workspace (~13 MB)
  char* ws = (char*)d_ws;
  unsigned short* gT2 = (unsigned short*)ws; ws += (size_t)N * F * 2;        // 2 MB
  unsigned int* bits = (unsigned int*)ws;    ws += (size_t)N * (N / 32) * 4; // 2 MB
  unsigned int* RT2 = (unsigned int*)ws;     ws += (size_t)N * NH * 4;
  unsigned short* BT = (unsigned short*)ws;  ws += (size_t)N * NH * 2;
  unsigned short* DT = (unsigned short*)ws;  ws += (size_t)N * NH * 2;
  float* U    = (float*)ws;                  ws += 16 * F * 4;
  float* parts  = (float*)ws;                ws += (size_t)NSPLIT * N * F * 4;  // 8 MB
  float* lparts = (float*)ws;                ws += (size_t)NSPLIT * N * NH * 4; // 256 KB

  k_u<<<dim3(16), dim3(256), 0, stream>>>(W, a, U);
  k_front<<<dim3(2560), dim3(256), 0, stream>>>(h, W, U, adj, RT2, BT, DT, gT2, bits);
  k_agg<<<dim3((N / TI) * 4 * NSPLIT), dim3(256), 0, stream>>>(
      gT2, RT2, BT, DT, bits, parts, lparts);
  k_norm<<<dim3(N * F / 4 / 256), dim3(256), 0, stream>>>(parts, lparts, out);
}